// Round 1
// baseline (2032.737 us; speedup 1.0000x reference)
//
#include <hip/hip_runtime.h>

#define N_NODES 50000
#define D_IN 128
#define D_HID 96
#define D_OUT 64

// deg[dst] += 1 per edge
__global__ void deg_kernel(const int* __restrict__ dst, float* __restrict__ deg, int E) {
    int e = blockIdx.x * blockDim.x + threadIdx.x;
    if (e < E) atomicAdd(&deg[dst[e]], 1.0f);
}

// in-place: deg -> rsqrt(deg + 1)   (+1 accounts for the self loop)
__global__ void dinv_kernel(float* __restrict__ deg, int n) {
    int i = blockIdx.x * blockDim.x + threadIdx.x;
    if (i < n) deg[i] = rsqrtf(deg[i] + 1.0f);
}

// H[row, col] = sum_k X[row,k] * W[k,col]
template <int K, int C>
__global__ void gemm_kernel(const float* __restrict__ X, const float* __restrict__ W,
                            float* __restrict__ H, int n) {
    int col = threadIdx.x;                          // [0, C)
    int row = blockIdx.x * blockDim.y + threadIdx.y;
    if (row >= n) return;
    const float* xr = X + (long)row * K;
    float acc = 0.f;
#pragma unroll
    for (int k = 0; k < K; ++k) acc += xr[k] * W[k * C + col];
    H[(long)row * C + col] = acc;
}

// out[dst] += H[src] * dinv[src] * dinv[dst], one thread per (edge, float4 quad)
template <int C>
__global__ void scatter_kernel(const int* __restrict__ src, const int* __restrict__ dst,
                               const float* __restrict__ dinv, const float* __restrict__ H,
                               float* __restrict__ out, int E) {
    constexpr int Q = C / 4;
    int gid = blockIdx.x * blockDim.x + threadIdx.x;
    int e = gid / Q;
    int q = gid - e * Q;
    if (e >= E) return;
    int s = src[e], d = dst[e];
    float nm = dinv[s] * dinv[d];
    float4 v = *(const float4*)(H + (long)s * C + q * 4);
    float* o = out + (long)d * C + q * 4;
    atomicAdd(o + 0, v.x * nm);
    atomicAdd(o + 1, v.y * nm);
    atomicAdd(o + 2, v.z * nm);
    atomicAdd(o + 3, v.w * nm);
}

// outbuf = relu(agg + H * dinv^2 + b)   (self-loop term fused, no atomics)
template <int C>
__global__ void finalize_kernel(const float* __restrict__ agg, const float* __restrict__ H,
                                const float* __restrict__ dinv, const float* __restrict__ b,
                                float* __restrict__ outbuf, int n) {
    int gid = blockIdx.x * blockDim.x + threadIdx.x;
    if (gid >= n * C) return;
    int i = gid / C, c = gid - i * C;
    float di = dinv[i];
    float v = agg[gid] + H[gid] * di * di + b[c];
    outbuf[gid] = fmaxf(v, 0.f);
}

extern "C" void kernel_launch(void* const* d_in, const int* in_sizes, int n_in,
                              void* d_out, int out_size, void* d_ws, size_t ws_size,
                              hipStream_t stream) {
    const float* x  = (const float*)d_in[0];
    const int*   ei = (const int*)d_in[1];
    const float* W1 = (const float*)d_in[2];
    const float* b1 = (const float*)d_in[3];
    const float* W2 = (const float*)d_in[4];
    const float* b2 = (const float*)d_in[5];
    float* out = (float*)d_out;

    const int n = in_sizes[0] / D_IN;       // 50000
    const int E = in_sizes[1] / 2;          // 800000
    const int* srcp = ei;                   // edge_index[0]
    const int* dstp = ei + E;               // edge_index[1]

    char* ws = (char*)d_ws;
    float* dinv = (float*)ws;                                   // n floats (~200 KB)
    float* h1   = (float*)(ws + (1 << 20));                     // n*96 f32 = 19.2 MB
    float* agg1 = (float*)(ws + (1 << 20) + 20u * 1024 * 1024); // n*96 f32 = 19.2 MB
    float* g2   = (float*)(ws + (1 << 20) + 40u * 1024 * 1024); // n*64 f32 = 12.8 MB

    // zero accumulators (d_out/d_ws are poisoned with 0xAA before every call)
    hipMemsetAsync(dinv, 0, (size_t)n * sizeof(float), stream);
    hipMemsetAsync(agg1, 0, (size_t)n * D_HID * sizeof(float), stream);
    hipMemsetAsync(out, 0, (size_t)n * D_OUT * sizeof(float), stream);

    // normalization
    deg_kernel<<<(E + 255) / 256, 256, 0, stream>>>(dstp, dinv, E);
    dinv_kernel<<<(n + 255) / 256, 256, 0, stream>>>(dinv, n);

    // layer 1
    {
        dim3 blk(D_HID, 2);
        gemm_kernel<D_IN, D_HID><<<(n + 1) / 2, blk, 0, stream>>>(x, W1, h1, n);
    }
    {
        long total = (long)E * (D_HID / 4);
        scatter_kernel<D_HID><<<(int)((total + 255) / 256), 256, 0, stream>>>(
            srcp, dstp, dinv, h1, agg1, E);
    }
    finalize_kernel<D_HID><<<(n * D_HID + 255) / 256, 256, 0, stream>>>(
        agg1, h1, dinv, b1, agg1, n);

    // layer 2
    {
        dim3 blk(D_OUT, 4);
        gemm_kernel<D_HID, D_OUT><<<(n + 3) / 4, blk, 0, stream>>>(agg1, W2, g2, n);
    }
    {
        long total = (long)E * (D_OUT / 4);
        scatter_kernel<D_OUT><<<(int)((total + 255) / 256), 256, 0, stream>>>(
            srcp, dstp, dinv, g2, out, E);
    }
    finalize_kernel<D_OUT><<<(n * D_OUT + 255) / 256, 256, 0, stream>>>(
        out, g2, dinv, b2, out, n);
}

// Round 2
// 574.613 us; speedup vs baseline: 3.5376x; 3.5376x over previous
//
#include <hip/hip_runtime.h>

#define D_IN 128
#define D_HID 96
#define D_OUT 64

// ---------- degree count (int atomics on 50K counters — cheap) ----------
__global__ void deg_kernel(const int* __restrict__ dst, int* __restrict__ deg, int E) {
    int e = blockIdx.x * blockDim.x + threadIdx.x;
    if (e < E) atomicAdd(&deg[dst[e]], 1);
}

// ---------- single-block exclusive scan over deg; also dinv + cursor ----------
__global__ void scan_kernel(const int* __restrict__ deg, int* __restrict__ row_ptr,
                            int* __restrict__ cursor, float* __restrict__ dinv, int n) {
    __shared__ int lds[1024];
    __shared__ int carry;
    const int tid = threadIdx.x;
    if (tid == 0) carry = 0;
    __syncthreads();
    for (int base = 0; base < n; base += 1024) {
        int i = base + tid;
        int v = (i < n) ? deg[i] : 0;
        if (i < n) dinv[i] = rsqrtf((float)v + 1.0f);   // +1 = self loop
        lds[tid] = v;
        __syncthreads();
        for (int off = 1; off < 1024; off <<= 1) {
            int t = (tid >= off) ? lds[tid - off] : 0;
            __syncthreads();
            lds[tid] += t;
            __syncthreads();
        }
        int excl = carry + lds[tid] - v;
        if (i < n) { row_ptr[i] = excl; cursor[i] = excl; }
        __syncthreads();
        if (tid == 1023) carry += lds[1023];
        __syncthreads();
    }
}

// ---------- bucket src indices by dst (counting sort body) ----------
__global__ void fill_kernel(const int* __restrict__ src, const int* __restrict__ dst,
                            int* __restrict__ cursor, int* __restrict__ srcIdx, int E) {
    int e = blockIdx.x * blockDim.x + threadIdx.x;
    if (e >= E) return;
    int d = dst[e];
    int pos = atomicAdd(&cursor[d], 1);
    srcIdx[pos] = src[e];
}

// ---------- H[row,:] = (X[row,:] @ W) * dinv[row] ----------
template <int K, int C>
__global__ void gemm_scaled_kernel(const float* __restrict__ X, const float* __restrict__ W,
                                   const float* __restrict__ dinv, float* __restrict__ H, int n) {
    int col = threadIdx.x;                              // [0, C)
    int row = blockIdx.x * blockDim.y + threadIdx.y;
    if (row >= n) return;
    const float* xr = X + (long)row * K;
    float acc = 0.f;
#pragma unroll
    for (int k = 0; k < K; ++k) acc = fmaf(xr[k], W[k * C + col], acc);
    H[(long)row * C + col] = acc * dinv[row];
}

// ---------- out[d,:] = relu(dinv[d] * (sum_{s in N(d)} hs[s,:] + hs[d,:]) + b) ----------
template <int C, int NY>
__global__ void agg_kernel(const int* __restrict__ row_ptr, const int* __restrict__ deg,
                           const int* __restrict__ srcIdx, const float* __restrict__ hs,
                           const float* __restrict__ dinv, const float* __restrict__ b,
                           float* __restrict__ out, int n) {
    int c = threadIdx.x;                                // [0, C)
    int d = blockIdx.x * NY + threadIdx.y;
    if (d >= n) return;
    int start = row_ptr[d];
    int cnt   = deg[d];
    float acc = hs[(long)d * C + c];                    // self-loop term
    int k = 0;
    for (; k + 1 < cnt; k += 2) {                       // 2 independent gathers/iter
        int s0 = srcIdx[start + k];
        int s1 = srcIdx[start + k + 1];
        acc += hs[(long)s0 * C + c];
        acc += hs[(long)s1 * C + c];
    }
    if (k < cnt) acc += hs[(long)srcIdx[start + k] * C + c];
    out[(long)d * C + c] = fmaxf(fmaf(dinv[d], acc, b[c]), 0.f);
}

extern "C" void kernel_launch(void* const* d_in, const int* in_sizes, int n_in,
                              void* d_out, int out_size, void* d_ws, size_t ws_size,
                              hipStream_t stream) {
    const float* x  = (const float*)d_in[0];
    const int*   ei = (const int*)d_in[1];
    const float* W1 = (const float*)d_in[2];
    const float* b1 = (const float*)d_in[3];
    const float* W2 = (const float*)d_in[4];
    const float* b2 = (const float*)d_in[5];
    float* out = (float*)d_out;

    const int n = in_sizes[0] / D_IN;       // 50000
    const int E = in_sizes[1] / 2;          // 800000
    const int* srcp = ei;                   // edge_index[0]
    const int* dstp = ei + E;               // edge_index[1]

    char* ws = (char*)d_ws;
    float* dinv   = (float*)(ws);                        // n f32      (256 KB slot)
    int*   deg    = (int*)  (ws + (256u << 10));         // n int
    int*   rowp   = (int*)  (ws + (512u << 10));         // n int
    int*   cursor = (int*)  (ws + (768u << 10));         // n int
    int*   srcIdx = (int*)  (ws + (1u << 20));           // E int      (4 MB slot)
    float* h1s    = (float*)(ws + (5u << 20));           // n*96 f32   (20 MB slot)
    float* act1   = (float*)(ws + (25u << 20));          // n*96 f32   (20 MB slot)
    float* g2s    = h1s;                                 // n*64 f32 — reuses h1s (dead by then)

    // deg must start at zero (ws is poisoned with 0xAA)
    hipMemsetAsync(deg, 0, (size_t)n * sizeof(int), stream);

    // CSR build
    deg_kernel<<<(E + 255) / 256, 256, 0, stream>>>(dstp, deg, E);
    scan_kernel<<<1, 1024, 0, stream>>>(deg, rowp, cursor, dinv, n);
    fill_kernel<<<(E + 255) / 256, 256, 0, stream>>>(srcp, dstp, cursor, srcIdx, E);

    // layer 1: h1s = (x @ W1) * dinv ; act1 = relu(dinv*(gather-sum + self) + b1)
    {
        dim3 blk(D_HID, 2);
        gemm_scaled_kernel<D_IN, D_HID><<<(n + 1) / 2, blk, 0, stream>>>(x, W1, dinv, h1s, n);
        agg_kernel<D_HID, 2><<<(n + 1) / 2, blk, 0, stream>>>(rowp, deg, srcIdx, h1s, dinv, b1, act1, n);
    }

    // layer 2: g2s = (act1 @ W2) * dinv ; out = relu(dinv*(gather-sum + self) + b2)
    {
        dim3 blk(D_OUT, 4);
        gemm_scaled_kernel<D_HID, D_OUT><<<(n + 3) / 4, blk, 0, stream>>>(act1, W2, dinv, g2s, n);
        agg_kernel<D_OUT, 4><<<(n + 3) / 4, blk, 0, stream>>>(rowp, deg, srcIdx, g2s, dinv, b2, out, n);
    }
}